// Round 10
// baseline (133.375 us; speedup 1.0000x reference)
//
#include <hip/hip_runtime.h>

#define B_  2
#define TQ  1024
#define TV  1024
#define DD  512
#define UU  128

#define QB  4            // q-rows per fused block

typedef __attribute__((ext_vector_type(8))) short short8;
typedef __attribute__((ext_vector_type(4))) float f32x4;

__device__ __forceinline__ unsigned short f2bf(float x){
    unsigned int u = __float_as_uint(x);
    unsigned int r = (u + 0x7FFFu + ((u >> 16) & 1u)) >> 16;
    return (unsigned short)r;
}
__device__ __forceinline__ float bf2f(unsigned short h){
    return __uint_as_float(((unsigned int)h) << 16);
}

// ---------------- projections + exp2 epilogue ----------------
// EQ = exp2(C*query@W1), EK = exp2(C*value@W2), C = 2*log2(e)
__global__ __launch_bounds__(256)
void proj_kernel(const float* __restrict__ query, const float* __restrict__ value,
                 const float* __restrict__ W1,    const float* __restrict__ W2,
                 float* __restrict__ eq, float* __restrict__ ek){
    const float TWO_LOG2E = 2.8853900817779268f;
    const float* X = blockIdx.z ? value : query;
    const float* W = blockIdx.z ? W2    : W1;
    float* out     = blockIdx.z ? ek    : eq;

    const int u    = threadIdx.x & 127;
    const int half = threadIdx.x >> 7;
    const int b    = blockIdx.y;
    const int t0   = blockIdx.x * 8 + half * 4;
    const float* x = X + ((size_t)b * TQ + t0) * DD;

    float acc0 = 0.f, acc1 = 0.f, acc2 = 0.f, acc3 = 0.f;
    for (int d = 0; d < DD; d += 4){
        float w0 = W[(d+0)*UU + u];
        float w1 = W[(d+1)*UU + u];
        float w2 = W[(d+2)*UU + u];
        float w3 = W[(d+3)*UU + u];
        float4 x0 = *reinterpret_cast<const float4*>(x + 0*DD + d);
        float4 x1 = *reinterpret_cast<const float4*>(x + 1*DD + d);
        float4 x2 = *reinterpret_cast<const float4*>(x + 2*DD + d);
        float4 x3 = *reinterpret_cast<const float4*>(x + 3*DD + d);
        acc0 = fmaf(x0.x,w0,acc0); acc0 = fmaf(x0.y,w1,acc0); acc0 = fmaf(x0.z,w2,acc0); acc0 = fmaf(x0.w,w3,acc0);
        acc1 = fmaf(x1.x,w0,acc1); acc1 = fmaf(x1.y,w1,acc1); acc1 = fmaf(x1.z,w2,acc1); acc1 = fmaf(x1.w,w3,acc1);
        acc2 = fmaf(x2.x,w0,acc2); acc2 = fmaf(x2.y,w1,acc2); acc2 = fmaf(x2.z,w2,acc2); acc2 = fmaf(x2.w,w3,acc2);
        acc3 = fmaf(x3.x,w0,acc3); acc3 = fmaf(x3.y,w1,acc3); acc3 = fmaf(x3.z,w2,acc3); acc3 = fmaf(x3.w,w3,acc3);
    }
    size_t o = ((size_t)b * TQ + t0) * UU + u;
    out[o + 0*UU] = __builtin_amdgcn_exp2f(TWO_LOG2E * acc0);
    out[o + 1*UU] = __builtin_amdgcn_exp2f(TWO_LOG2E * acc1);
    out[o + 2*UU] = __builtin_amdgcn_exp2f(TWO_LOG2E * acc2);
    out[o + 3*UU] = __builtin_amdgcn_exp2f(TWO_LOG2E * acc3);
}

// ---------------- fused scores + softmax ----------------
// scores[q,k] = sum_u (-2*scale[u]) * rcp(1 + EQ[q,u]*EK[k,u])  (+const, cancels)
// block = 8 waves, owns QB=4 q-rows x all 1024 k. Wave w: k in {w*128+lane, +64}.
// Scores -> LDS -> in-block softmax -> write attn weights only.
__global__ __launch_bounds__(512, 4)
void fused_kernel(const float* __restrict__ eq, const float* __restrict__ ek,
                  const float* __restrict__ scale, float* __restrict__ attn){
    __shared__ float qs[QB][UU];
    __shared__ float sc[UU];
    __shared__ float sm[QB][TV];     // 16 KB score staging

    const float LOG2E = 1.4426950408889634f;
    const int b   = blockIdx.y;
    const int q0  = blockIdx.x * QB;
    const int tid = threadIdx.x;
    const int w   = tid >> 6, lane = tid & 63;

    if (tid < QB*UU)
        qs[tid >> 7][tid & 127] = eq[((size_t)b * TQ + q0 + (tid >> 7)) * UU + (tid & 127)];
    if (tid < UU)
        sc[tid] = -2.0f * scale[tid];
    __syncthreads();

    const float4* ekv = reinterpret_cast<const float4*>(ek + (size_t)b * TV * UU);
    const float4* qs4 = reinterpret_cast<const float4*>(&qs[0][0]);   // row r: qs4[r*32 + j]
    const float4* sc4 = reinterpret_cast<const float4*>(&sc[0]);

    const int kA = w*128 + lane;                // first k this lane owns
    const int kB = kA + 64;                     // second
    const size_t iA = (size_t)kA * 32;          // float4 index base
    const size_t iB = (size_t)kB * 32;

    float accA[QB] = {};
    float accB[QB] = {};
    float4 kva = ekv[iA];
    float4 kvb = ekv[iB];

    for (int j = 0; j < 32; ++j){
        float4 nka, nkb;
        if (j != 31){ nka = ekv[iA + j + 1]; nkb = ekv[iB + j + 1]; }
        float4 s4 = sc4[j];
        #pragma unroll
        for (int r = 0; r < QB; ++r){
            float4 q4 = qs4[r*32 + j];
            accA[r] = fmaf(s4.x, __builtin_amdgcn_rcpf(fmaf(q4.x, kva.x, 1.0f)), accA[r]);
            accA[r] = fmaf(s4.y, __builtin_amdgcn_rcpf(fmaf(q4.y, kva.y, 1.0f)), accA[r]);
            accA[r] = fmaf(s4.z, __builtin_amdgcn_rcpf(fmaf(q4.z, kva.z, 1.0f)), accA[r]);
            accA[r] = fmaf(s4.w, __builtin_amdgcn_rcpf(fmaf(q4.w, kva.w, 1.0f)), accA[r]);
            accB[r] = fmaf(s4.x, __builtin_amdgcn_rcpf(fmaf(q4.x, kvb.x, 1.0f)), accB[r]);
            accB[r] = fmaf(s4.y, __builtin_amdgcn_rcpf(fmaf(q4.y, kvb.y, 1.0f)), accB[r]);
            accB[r] = fmaf(s4.z, __builtin_amdgcn_rcpf(fmaf(q4.z, kvb.z, 1.0f)), accB[r]);
            accB[r] = fmaf(s4.w, __builtin_amdgcn_rcpf(fmaf(q4.w, kvb.w, 1.0f)), accB[r]);
        }
        kva = nka; kvb = nkb;
    }

    #pragma unroll
    for (int r = 0; r < QB; ++r){
        sm[r][kA] = accA[r];
        sm[r][kB] = accB[r];
    }
    __syncthreads();

    // softmax: wave r (<QB) handles row r (16 elements/lane)
    if (w < QB){
        float s[16];
        #pragma unroll
        for (int t = 0; t < 16; ++t) s[t] = sm[w][t*64 + lane];

        float m = s[0];
        #pragma unroll
        for (int t = 1; t < 16; ++t) m = fmaxf(m, s[t]);
        #pragma unroll
        for (int off = 32; off >= 1; off >>= 1) m = fmaxf(m, __shfl_xor(m, off, 64));
        float sum = 0.f;
        #pragma unroll
        for (int t = 0; t < 16; ++t){ s[t] = __builtin_amdgcn_exp2f((s[t] - m) * LOG2E); sum += s[t]; }
        #pragma unroll
        for (int off = 32; off >= 1; off >>= 1) sum += __shfl_xor(sum, off, 64);
        float inv = 1.0f / sum;

        float* arow = attn + ((size_t)b * TQ + q0 + w) * TV;
        #pragma unroll
        for (int t = 0; t < 16; ++t) arow[t*64 + lane] = s[t] * inv;
    }
}

// ---------------- context = attn @ value via bf16-split MFMA ----------------
// ctx = (ah+al)@(vh+vl) ~= ah@vh + al@vh + ah@vl  (fp32 MFMA accum)
__global__ __launch_bounds__(256)
void ctx_kernel(const float* __restrict__ attn, const float* __restrict__ value,
                float* __restrict__ ctx){
    __shared__ unsigned short Ah[64*64], Al[64*64], Vh[64*64], Vl[64*64];

    const int m0   = blockIdx.x * 64;        // global row in [0, B*TQ)
    const int n0   = blockIdx.y * 64;
    const int b    = m0 >> 10;
    const int tid  = threadIdx.x;
    const int lane = tid & 63;
    const int w    = tid >> 6;
    const int wm   = w >> 1, wn = w & 1;

    const int am = tid >> 2;
    const int kq = (tid & 3) * 16;

    const float* arow  = attn  + (size_t)(m0 + am) * TV;
    const float* vbase = value + (size_t)b * TV * DD + n0 + am;

    float ra[16];
    float rv[16];
    #pragma unroll
    for (int i = 0; i < 4; ++i)
        *reinterpret_cast<float4*>(&ra[i*4]) = *reinterpret_cast<const float4*>(arow + kq + i*4);
    #pragma unroll
    for (int e = 0; e < 16; ++e) rv[e] = vbase[(size_t)(kq + e) * DD];

    f32x4 acc[2][2];
    #pragma unroll
    for (int i = 0; i < 2; ++i)
        #pragma unroll
        for (int j = 0; j < 2; ++j)
            acc[i][j] = (f32x4){0.f, 0.f, 0.f, 0.f};

    for (int kt = 0; kt < TV; kt += 64){
        #pragma unroll
        for (int gg = 0; gg < 2; ++gg){
            unsigned short h8[8], l8[8], vh8[8], vl8[8];
            #pragma unroll
            for (int e = 0; e < 8; ++e){
                float a = ra[gg*8 + e];
                unsigned short h = f2bf(a);
                h8[e] = h; l8[e] = f2bf(a - bf2f(h));
                float v = rv[gg*8 + e];
                unsigned short vh = f2bf(v);
                vh8[e] = vh; vl8[e] = f2bf(v - bf2f(vh));
            }
            int g = ((kq >> 3) + gg) ^ (am & 7);
            *reinterpret_cast<int4*>(&Ah[am*64 + g*8]) = *reinterpret_cast<const int4*>(h8);
            *reinterpret_cast<int4*>(&Al[am*64 + g*8]) = *reinterpret_cast<const int4*>(l8);
            *reinterpret_cast<int4*>(&Vh[am*64 + g*8]) = *reinterpret_cast<const int4*>(vh8);
            *reinterpret_cast<int4*>(&Vl[am*64 + g*8]) = *reinterpret_cast<const int4*>(vl8);
        }

        const int ktn = (kt + 64 < TV) ? kt + 64 : 0;
        #pragma unroll
        for (int i = 0; i < 4; ++i)
            *reinterpret_cast<float4*>(&ra[i*4]) = *reinterpret_cast<const float4*>(arow + ktn + kq + i*4);
        #pragma unroll
        for (int e = 0; e < 16; ++e) rv[e] = vbase[(size_t)(ktn + kq + e) * DD];

        __syncthreads();

        #pragma unroll
        for (int kk = 0; kk < 2; ++kk){
            const int kg = kk*4 + (lane >> 4);
            const int g  = (kg ^ (lane & 7)) * 8;
            const int r0 = (wm*32 + (lane & 15)) * 64;
            const int c0 = (wn*32 + (lane & 15)) * 64;

            short8 a0h = *reinterpret_cast<const short8*>(&Ah[r0 + g]);
            short8 a1h = *reinterpret_cast<const short8*>(&Ah[r0 + 16*64 + g]);
            short8 a0l = *reinterpret_cast<const short8*>(&Al[r0 + g]);
            short8 a1l = *reinterpret_cast<const short8*>(&Al[r0 + 16*64 + g]);
            short8 b0h = *reinterpret_cast<const short8*>(&Vh[c0 + g]);
            short8 b1h = *reinterpret_cast<const short8*>(&Vh[c0 + 16*64 + g]);
            short8 b0l = *reinterpret_cast<const short8*>(&Vl[c0 + g]);
            short8 b1l = *reinterpret_cast<const short8*>(&Vl[c0 + 16*64 + g]);

            acc[0][0] = __builtin_amdgcn_mfma_f32_16x16x32_bf16(a0h, b0h, acc[0][0], 0, 0, 0);
            acc[0][0] = __builtin_amdgcn_mfma_f32_16x16x32_bf16(a0l, b0h, acc[0][0], 0, 0, 0);
            acc[0][0] = __builtin_amdgcn_mfma_f32_16x16x32_bf16(a0h, b0l, acc[0][0], 0, 0, 0);

            acc[0][1] = __builtin_amdgcn_mfma_f32_16x16x32_bf16(a0h, b1h, acc[0][1], 0, 0, 0);
            acc[0][1] = __builtin_amdgcn_mfma_f32_16x16x32_bf16(a0l, b1h, acc[0][1], 0, 0, 0);
            acc[0][1] = __builtin_amdgcn_mfma_f32_16x16x32_bf16(a0h, b1l, acc[0][1], 0, 0, 0);

            acc[1][0] = __builtin_amdgcn_mfma_f32_16x16x32_bf16(a1h, b0h, acc[1][0], 0, 0, 0);
            acc[1][0] = __builtin_amdgcn_mfma_f32_16x16x32_bf16(a1l, b0h, acc[1][0], 0, 0, 0);
            acc[1][0] = __builtin_amdgcn_mfma_f32_16x16x32_bf16(a1h, b0l, acc[1][0], 0, 0, 0);

            acc[1][1] = __builtin_amdgcn_mfma_f32_16x16x32_bf16(a1h, b1h, acc[1][1], 0, 0, 0);
            acc[1][1] = __builtin_amdgcn_mfma_f32_16x16x32_bf16(a1l, b1h, acc[1][1], 0, 0, 0);
            acc[1][1] = __builtin_amdgcn_mfma_f32_16x16x32_bf16(a1h, b1l, acc[1][1], 0, 0, 0);
        }

        __syncthreads();
    }

    #pragma unroll
    for (int fm = 0; fm < 2; ++fm){
        #pragma unroll
        for (int fn = 0; fn < 2; ++fn){
            const int row = m0 + wm*32 + fm*16 + (lane >> 4) * 4;
            const int col = n0 + wn*32 + fn*16 + (lane & 15);
            #pragma unroll
            for (int r = 0; r < 4; ++r)
                ctx[(size_t)(row + r) * DD + col] = acc[fm][fn][r];
        }
    }
}

extern "C" void kernel_launch(void* const* d_in, const int* in_sizes, int n_in,
                              void* d_out, int out_size, void* d_ws, size_t ws_size,
                              hipStream_t stream){
    const float* query = (const float*)d_in[0];
    const float* value = (const float*)d_in[1];
    const float* W1    = (const float*)d_in[2];
    const float* W2    = (const float*)d_in[3];
    const float* scale = (const float*)d_in[4];

    float* eq = (float*)d_ws;                              // 1 MB
    float* ek = eq + (size_t)B_ * TQ * UU;                 // 1 MB

    float* out  = (float*)d_out;
    float* ctx  = out;                                     // [B][TQ][DD]
    float* attn = out + (size_t)B_ * TQ * DD;              // [B][TQ][TV]

    proj_kernel<<<dim3(TQ/8, B_, 2), 256, 0, stream>>>(query, value, W1, W2, eq, ek);
    fused_kernel<<<dim3(TQ/QB, B_), 512, 0, stream>>>(eq, ek, scale, attn);
    ctx_kernel<<<dim3((B_*TQ)/64, DD/64), 256, 0, stream>>>(attn, value, ctx);
}

// Round 11
// 108.615 us; speedup vs baseline: 1.2280x; 1.2280x over previous
//
#include <hip/hip_runtime.h>

#define B_  2
#define TQ  1024
#define TV  1024
#define DD  512
#define UU  128

#define QB  4            // q-rows per fused block

typedef __attribute__((ext_vector_type(8))) short short8;
typedef __attribute__((ext_vector_type(4))) float f32x4;

__device__ __forceinline__ unsigned short f2bf(float x){
    unsigned int u = __float_as_uint(x);
    unsigned int r = (u + 0x7FFFu + ((u >> 16) & 1u)) >> 16;
    return (unsigned short)r;
}
__device__ __forceinline__ float bf2f(unsigned short h){
    return __uint_as_float(((unsigned int)h) << 16);
}

// ---------------- projections + exp2 epilogue ----------------
// EQ = exp2(C*query@W1), EK = exp2(C*value@W2), C = 2*log2(e)
__global__ __launch_bounds__(256)
void proj_kernel(const float* __restrict__ query, const float* __restrict__ value,
                 const float* __restrict__ W1,    const float* __restrict__ W2,
                 float* __restrict__ eq, float* __restrict__ ek){
    const float TWO_LOG2E = 2.8853900817779268f;
    const float* X = blockIdx.z ? value : query;
    const float* W = blockIdx.z ? W2    : W1;
    float* out     = blockIdx.z ? ek    : eq;

    const int u    = threadIdx.x & 127;
    const int half = threadIdx.x >> 7;
    const int b    = blockIdx.y;
    const int t0   = blockIdx.x * 8 + half * 4;
    const float* x = X + ((size_t)b * TQ + t0) * DD;

    float acc0 = 0.f, acc1 = 0.f, acc2 = 0.f, acc3 = 0.f;
    for (int d = 0; d < DD; d += 4){
        float w0 = W[(d+0)*UU + u];
        float w1 = W[(d+1)*UU + u];
        float w2 = W[(d+2)*UU + u];
        float w3 = W[(d+3)*UU + u];
        float4 x0 = *reinterpret_cast<const float4*>(x + 0*DD + d);
        float4 x1 = *reinterpret_cast<const float4*>(x + 1*DD + d);
        float4 x2 = *reinterpret_cast<const float4*>(x + 2*DD + d);
        float4 x3 = *reinterpret_cast<const float4*>(x + 3*DD + d);
        acc0 = fmaf(x0.x,w0,acc0); acc0 = fmaf(x0.y,w1,acc0); acc0 = fmaf(x0.z,w2,acc0); acc0 = fmaf(x0.w,w3,acc0);
        acc1 = fmaf(x1.x,w0,acc1); acc1 = fmaf(x1.y,w1,acc1); acc1 = fmaf(x1.z,w2,acc1); acc1 = fmaf(x1.w,w3,acc1);
        acc2 = fmaf(x2.x,w0,acc2); acc2 = fmaf(x2.y,w1,acc2); acc2 = fmaf(x2.z,w2,acc2); acc2 = fmaf(x2.w,w3,acc2);
        acc3 = fmaf(x3.x,w0,acc3); acc3 = fmaf(x3.y,w1,acc3); acc3 = fmaf(x3.z,w2,acc3); acc3 = fmaf(x3.w,w3,acc3);
    }
    size_t o = ((size_t)b * TQ + t0) * UU + u;
    out[o + 0*UU] = __builtin_amdgcn_exp2f(TWO_LOG2E * acc0);
    out[o + 1*UU] = __builtin_amdgcn_exp2f(TWO_LOG2E * acc1);
    out[o + 2*UU] = __builtin_amdgcn_exp2f(TWO_LOG2E * acc2);
    out[o + 3*UU] = __builtin_amdgcn_exp2f(TWO_LOG2E * acc3);
}

// ---------------- fused scores + softmax ----------------
// 1024 threads = 16 waves; block owns QB=4 q-rows x all 1024 k (1 k per lane).
// grid 512 -> 2 blocks/CU x 16 waves = 32 waves/CU (the occupancy r7 showed is needed).
// Softmax distributed: wave w -> row w&3, k-segment (w>>2)*256.
__global__ __launch_bounds__(1024, 8)
void fused_kernel(const float* __restrict__ eq, const float* __restrict__ ek,
                  const float* __restrict__ scale, float* __restrict__ attn){
    __shared__ float qs[QB][UU];
    __shared__ float sc[UU];
    __shared__ float sm[QB][TV];     // 16 KB score staging
    __shared__ float pmax[QB][4];
    __shared__ float psum[QB][4];

    const float LOG2E = 1.4426950408889634f;
    const int b   = blockIdx.y;
    const int q0  = blockIdx.x * QB;
    const int tid = threadIdx.x;
    const int w   = tid >> 6, lane = tid & 63;

    if (tid < QB*UU)
        qs[tid >> 7][tid & 127] = eq[((size_t)b * TQ + q0 + (tid >> 7)) * UU + (tid & 127)];
    if (tid < UU)
        sc[tid] = -2.0f * scale[tid];
    __syncthreads();

    const float4* ekv = reinterpret_cast<const float4*>(ek + (size_t)b * TV * UU);
    const float4* qs4 = reinterpret_cast<const float4*>(&qs[0][0]);   // row r: qs4[r*32 + j]
    const float4* sc4 = reinterpret_cast<const float4*>(&sc[0]);

    const int kA = w*64 + lane;                 // the k this lane owns
    const size_t iA = (size_t)kA * 32;          // float4 index base

    float acc[QB] = {};
    float4 kva = ekv[iA];

    for (int j = 0; j < 32; ++j){
        float4 nka;
        if (j != 31) nka = ekv[iA + j + 1];
        float4 s4 = sc4[j];
        #pragma unroll
        for (int r = 0; r < QB; ++r){
            float4 q4 = qs4[r*32 + j];
            acc[r] = fmaf(s4.x, __builtin_amdgcn_rcpf(fmaf(q4.x, kva.x, 1.0f)), acc[r]);
            acc[r] = fmaf(s4.y, __builtin_amdgcn_rcpf(fmaf(q4.y, kva.y, 1.0f)), acc[r]);
            acc[r] = fmaf(s4.z, __builtin_amdgcn_rcpf(fmaf(q4.z, kva.z, 1.0f)), acc[r]);
            acc[r] = fmaf(s4.w, __builtin_amdgcn_rcpf(fmaf(q4.w, kva.w, 1.0f)), acc[r]);
        }
        kva = nka;
    }

    #pragma unroll
    for (int r = 0; r < QB; ++r) sm[r][kA] = acc[r];
    __syncthreads();

    // distributed softmax: wave w -> row r = w&3, segment seg = w>>2 (256 k)
    {
        const int r   = w & 3;
        const int seg = w >> 2;
        float s[4];
        #pragma unroll
        for (int t = 0; t < 4; ++t) s[t] = sm[r][seg*256 + t*64 + lane];

        float m = fmaxf(fmaxf(s[0], s[1]), fmaxf(s[2], s[3]));
        #pragma unroll
        for (int off = 32; off >= 1; off >>= 1) m = fmaxf(m, __shfl_xor(m, off, 64));
        if (lane == 0) pmax[r][seg] = m;
        __syncthreads();

        float M = fmaxf(fmaxf(pmax[r][0], pmax[r][1]), fmaxf(pmax[r][2], pmax[r][3]));
        float sum = 0.f;
        #pragma unroll
        for (int t = 0; t < 4; ++t){ s[t] = __builtin_amdgcn_exp2f((s[t] - M) * LOG2E); sum += s[t]; }
        #pragma unroll
        for (int off = 32; off >= 1; off >>= 1) sum += __shfl_xor(sum, off, 64);
        if (lane == 0) psum[r][seg] = sum;
        __syncthreads();

        float S = (psum[r][0] + psum[r][1]) + (psum[r][2] + psum[r][3]);
        float inv = 1.0f / S;

        float* arow = attn + ((size_t)b * TQ + q0 + r) * TV + seg*256;
        #pragma unroll
        for (int t = 0; t < 4; ++t) arow[t*64 + lane] = s[t] * inv;
    }
}

// ---------------- context = attn @ value via bf16-split MFMA ----------------
// ctx = (ah+al)@(vh+vl) ~= ah@vh + al@vh + ah@vl  (fp32 MFMA accum)
// Tile 64x32, K-step 64, 4 waves (2m x 2n), grid 512 = 2 blocks/CU.
__global__ __launch_bounds__(256, 4)
void ctx_kernel(const float* __restrict__ attn, const float* __restrict__ value,
                float* __restrict__ ctx){
    __shared__ unsigned short Ah[64*64], Al[64*64], Vh[32*64], Vl[32*64];

    const int m0   = blockIdx.x * 64;        // global row in [0, B*TQ)
    const int n0   = blockIdx.y * 32;
    const int b    = m0 >> 10;
    const int tid  = threadIdx.x;
    const int lane = tid & 63;
    const int w    = tid >> 6;
    const int wm   = w >> 1, wn = w & 1;

    // A staging: row am (0..63), k-chunk kq (16 elems); V staging: col cn (0..31), k-chunk kv (8)
    const int am = tid >> 2;
    const int kq = (tid & 3) * 16;
    const int cn = tid >> 3;
    const int kv = (tid & 7) * 8;

    const float* arow = attn  + (size_t)(m0 + am) * TV;
    const float* vcol = value + (size_t)b * TV * DD + n0 + cn;

    float ra[16];
    float rv[8];
    #pragma unroll
    for (int i = 0; i < 4; ++i)
        *reinterpret_cast<float4*>(&ra[i*4]) = *reinterpret_cast<const float4*>(arow + kq + i*4);
    #pragma unroll
    for (int e = 0; e < 8; ++e) rv[e] = vcol[(size_t)(kv + e) * DD];

    f32x4 acc[2];
    acc[0] = (f32x4){0.f,0.f,0.f,0.f};
    acc[1] = (f32x4){0.f,0.f,0.f,0.f};

    for (int kt = 0; kt < TV; kt += 64){
        // convert + stage A (two 8-elem groups) and V (one 8-elem group)
        #pragma unroll
        for (int gg = 0; gg < 2; ++gg){
            unsigned short h8[8], l8[8];
            #pragma unroll
            for (int e = 0; e < 8; ++e){
                float a = ra[gg*8 + e];
                unsigned short h = f2bf(a);
                h8[e] = h; l8[e] = f2bf(a - bf2f(h));
            }
            int g = ((kq >> 3) + gg) ^ (am & 7);
            *reinterpret_cast<int4*>(&Ah[am*64 + g*8]) = *reinterpret_cast<const int4*>(h8);
            *reinterpret_cast<int4*>(&Al[am*64 + g*8]) = *reinterpret_cast<const int4*>(l8);
        }
        {
            unsigned short vh8[8], vl8[8];
            #pragma unroll
            for (int e = 0; e < 8; ++e){
                float v = rv[e];
                unsigned short vh = f2bf(v);
                vh8[e] = vh; vl8[e] = f2bf(v - bf2f(vh));
            }
            int g = (kv >> 3) ^ (cn & 7);
            *reinterpret_cast<int4*>(&Vh[cn*64 + g*8]) = *reinterpret_cast<const int4*>(vh8);
            *reinterpret_cast<int4*>(&Vl[cn*64 + g*8]) = *reinterpret_cast<const int4*>(vl8);
        }

        // prefetch next k-tile
        const int ktn = (kt + 64 < TV) ? kt + 64 : 0;
        #pragma unroll
        for (int i = 0; i < 4; ++i)
            *reinterpret_cast<float4*>(&ra[i*4]) = *reinterpret_cast<const float4*>(arow + ktn + kq + i*4);
        #pragma unroll
        for (int e = 0; e < 8; ++e) rv[e] = vcol[(size_t)(ktn + kv + e) * DD];

        __syncthreads();

        #pragma unroll
        for (int kk = 0; kk < 2; ++kk){
            const int kg = kk*4 + (lane >> 4);
            const int g  = (kg ^ (lane & 7)) * 8;
            const int r0 = (wm*32 + (lane & 15)) * 64;
            const int c0 = (wn*16 + (lane & 15)) * 64;

            short8 a0h = *reinterpret_cast<const short8*>(&Ah[r0 + g]);
            short8 a1h = *reinterpret_cast<const short8*>(&Ah[r0 + 16*64 + g]);
            short8 a0l = *reinterpret_cast<const short8*>(&Al[r0 + g]);
            short8 a1l = *reinterpret_cast<const short8*>(&Al[r0 + 16*64 + g]);
            short8 bh  = *reinterpret_cast<const short8*>(&Vh[c0 + g]);
            short8 bl  = *reinterpret_cast<const short8*>(&Vl[c0 + g]);

            acc[0] = __builtin_amdgcn_mfma_f32_16x16x32_bf16(a0h, bh, acc[0], 0, 0, 0);
            acc[0] = __builtin_amdgcn_mfma_f32_16x16x32_bf16(a0l, bh, acc[0], 0, 0, 0);
            acc[0] = __builtin_amdgcn_mfma_f32_16x16x32_bf16(a0h, bl, acc[0], 0, 0, 0);

            acc[1] = __builtin_amdgcn_mfma_f32_16x16x32_bf16(a1h, bh, acc[1], 0, 0, 0);
            acc[1] = __builtin_amdgcn_mfma_f32_16x16x32_bf16(a1l, bh, acc[1], 0, 0, 0);
            acc[1] = __builtin_amdgcn_mfma_f32_16x16x32_bf16(a1h, bl, acc[1], 0, 0, 0);
        }

        __syncthreads();
    }

    #pragma unroll
    for (int fm = 0; fm < 2; ++fm){
        const int row = m0 + wm*32 + fm*16 + (lane >> 4) * 4;
        const int col = n0 + wn*16 + (lane & 15);
        #pragma unroll
        for (int r = 0; r < 4; ++r)
            ctx[(size_t)(row + r) * DD + col] = acc[fm][r];
    }
}

extern "C" void kernel_launch(void* const* d_in, const int* in_sizes, int n_in,
                              void* d_out, int out_size, void* d_ws, size_t ws_size,
                              hipStream_t stream){
    const float* query = (const float*)d_in[0];
    const float* value = (const float*)d_in[1];
    const float* W1    = (const float*)d_in[2];
    const float* W2    = (const float*)d_in[3];
    const float* scale = (const float*)d_in[4];

    float* eq = (float*)d_ws;                              // 1 MB
    float* ek = eq + (size_t)B_ * TQ * UU;                 // 1 MB

    float* out  = (float*)d_out;
    float* ctx  = out;                                     // [B][TQ][DD]
    float* attn = out + (size_t)B_ * TQ * DD;              // [B][TQ][TV]

    proj_kernel<<<dim3(TQ/8, B_, 2), 256, 0, stream>>>(query, value, W1, W2, eq, ek);
    fused_kernel<<<dim3(TQ/QB, B_), 1024, 0, stream>>>(eq, ek, scale, attn);
    ctx_kernel<<<dim3((B_*TQ)/64, DD/32), 256, 0, stream>>>(attn, value, ctx);
}

// Round 12
// 103.274 us; speedup vs baseline: 1.2915x; 1.0517x over previous
//
#include <hip/hip_runtime.h>

#define B_  2
#define TQ  1024
#define TV  1024
#define DD  512
#define UU  128

#define QB  4            // q-rows per fused block

typedef __attribute__((ext_vector_type(8))) short short8;
typedef __attribute__((ext_vector_type(4))) float f32x4;

__device__ __forceinline__ unsigned short f2bf(float x){
    unsigned int u = __float_as_uint(x);
    unsigned int r = (u + 0x7FFFu + ((u >> 16) & 1u)) >> 16;
    return (unsigned short)r;
}
__device__ __forceinline__ float bf2f(unsigned short h){
    return __uint_as_float(((unsigned int)h) << 16);
}

// ---------------- projections + exp2 epilogue ----------------
// EQ = exp2(C*query@W1), EK = exp2(C*value@W2), C = 2*log2(e)
__global__ __launch_bounds__(256)
void proj_kernel(const float* __restrict__ query, const float* __restrict__ value,
                 const float* __restrict__ W1,    const float* __restrict__ W2,
                 float* __restrict__ eq, float* __restrict__ ek){
    const float TWO_LOG2E = 2.8853900817779268f;
    const float* X = blockIdx.z ? value : query;
    const float* W = blockIdx.z ? W2    : W1;
    float* out     = blockIdx.z ? ek    : eq;

    const int u    = threadIdx.x & 127;
    const int half = threadIdx.x >> 7;
    const int b    = blockIdx.y;
    const int t0   = blockIdx.x * 8 + half * 4;
    const float* x = X + ((size_t)b * TQ + t0) * DD;

    float acc0 = 0.f, acc1 = 0.f, acc2 = 0.f, acc3 = 0.f;
    for (int d = 0; d < DD; d += 4){
        float w0 = W[(d+0)*UU + u];
        float w1 = W[(d+1)*UU + u];
        float w2 = W[(d+2)*UU + u];
        float w3 = W[(d+3)*UU + u];
        float4 x0 = *reinterpret_cast<const float4*>(x + 0*DD + d);
        float4 x1 = *reinterpret_cast<const float4*>(x + 1*DD + d);
        float4 x2 = *reinterpret_cast<const float4*>(x + 2*DD + d);
        float4 x3 = *reinterpret_cast<const float4*>(x + 3*DD + d);
        acc0 = fmaf(x0.x,w0,acc0); acc0 = fmaf(x0.y,w1,acc0); acc0 = fmaf(x0.z,w2,acc0); acc0 = fmaf(x0.w,w3,acc0);
        acc1 = fmaf(x1.x,w0,acc1); acc1 = fmaf(x1.y,w1,acc1); acc1 = fmaf(x1.z,w2,acc1); acc1 = fmaf(x1.w,w3,acc1);
        acc2 = fmaf(x2.x,w0,acc2); acc2 = fmaf(x2.y,w1,acc2); acc2 = fmaf(x2.z,w2,acc2); acc2 = fmaf(x2.w,w3,acc2);
        acc3 = fmaf(x3.x,w0,acc3); acc3 = fmaf(x3.y,w1,acc3); acc3 = fmaf(x3.z,w2,acc3); acc3 = fmaf(x3.w,w3,acc3);
    }
    size_t o = ((size_t)b * TQ + t0) * UU + u;
    out[o + 0*UU] = __builtin_amdgcn_exp2f(TWO_LOG2E * acc0);
    out[o + 1*UU] = __builtin_amdgcn_exp2f(TWO_LOG2E * acc1);
    out[o + 2*UU] = __builtin_amdgcn_exp2f(TWO_LOG2E * acc2);
    out[o + 3*UU] = __builtin_amdgcn_exp2f(TWO_LOG2E * acc3);
}

// ---------------- V transpose + bf16 h/l split (one-shot) ----------------
// value [b][k][d] fp32 -> vht/vlt [b][d][k] bf16 planes
__global__ __launch_bounds__(256)
void vsplit_kernel(const float* __restrict__ value,
                   unsigned short* __restrict__ vht, unsigned short* __restrict__ vlt){
    __shared__ float t[64][65];
    const int b  = blockIdx.z;
    const int k0 = blockIdx.x * 64;
    const int d0 = blockIdx.y * 64;
    const int tid = threadIdx.x;

    #pragma unroll
    for (int i = 0; i < 4; ++i){
        int r = (tid >> 4) + 16*i;
        int c = (tid & 15) * 4;
        float4 v = *reinterpret_cast<const float4*>(value + ((size_t)b*TV + k0 + r)*DD + d0 + c);
        t[r][c+0]=v.x; t[r][c+1]=v.y; t[r][c+2]=v.z; t[r][c+3]=v.w;
    }
    __syncthreads();

    const int dr = tid >> 2;            // 0..63 output d-row
    const int kc = (tid & 3) * 16;      // k chunk
    #pragma unroll
    for (int g = 0; g < 2; ++g){
        unsigned short h8[8], l8[8];
        #pragma unroll
        for (int e = 0; e < 8; ++e){
            float v = t[kc + g*8 + e][dr];
            unsigned short h = f2bf(v);
            h8[e] = h; l8[e] = f2bf(v - bf2f(h));
        }
        size_t o = ((size_t)b*DD + d0 + dr)*TV + k0 + kc + g*8;
        *reinterpret_cast<int4*>(vht + o) = *reinterpret_cast<const int4*>(h8);
        *reinterpret_cast<int4*>(vlt + o) = *reinterpret_cast<const int4*>(l8);
    }
}

// ---------------- fused scores + softmax ----------------
// 1024 threads = 16 waves; block owns QB=4 q-rows x all 1024 k (1 k per lane).
__global__ __launch_bounds__(1024, 8)
void fused_kernel(const float* __restrict__ eq, const float* __restrict__ ek,
                  const float* __restrict__ scale, float* __restrict__ attn){
    __shared__ float qs[QB][UU];
    __shared__ float sc[UU];
    __shared__ float sm[QB][TV];
    __shared__ float pmax[QB][4];
    __shared__ float psum[QB][4];

    const float LOG2E = 1.4426950408889634f;
    const int b   = blockIdx.y;
    const int q0  = blockIdx.x * QB;
    const int tid = threadIdx.x;
    const int w   = tid >> 6, lane = tid & 63;

    if (tid < QB*UU)
        qs[tid >> 7][tid & 127] = eq[((size_t)b * TQ + q0 + (tid >> 7)) * UU + (tid & 127)];
    if (tid < UU)
        sc[tid] = -2.0f * scale[tid];
    __syncthreads();

    const float4* ekv = reinterpret_cast<const float4*>(ek + (size_t)b * TV * UU);
    const float4* qs4 = reinterpret_cast<const float4*>(&qs[0][0]);
    const float4* sc4 = reinterpret_cast<const float4*>(&sc[0]);

    const int kA = w*64 + lane;
    const size_t iA = (size_t)kA * 32;

    float acc[QB] = {};
    float4 kva = ekv[iA];

    for (int j = 0; j < 32; ++j){
        float4 nka;
        if (j != 31) nka = ekv[iA + j + 1];
        float4 s4 = sc4[j];
        #pragma unroll
        for (int r = 0; r < QB; ++r){
            float4 q4 = qs4[r*32 + j];
            acc[r] = fmaf(s4.x, __builtin_amdgcn_rcpf(fmaf(q4.x, kva.x, 1.0f)), acc[r]);
            acc[r] = fmaf(s4.y, __builtin_amdgcn_rcpf(fmaf(q4.y, kva.y, 1.0f)), acc[r]);
            acc[r] = fmaf(s4.z, __builtin_amdgcn_rcpf(fmaf(q4.z, kva.z, 1.0f)), acc[r]);
            acc[r] = fmaf(s4.w, __builtin_amdgcn_rcpf(fmaf(q4.w, kva.w, 1.0f)), acc[r]);
        }
        kva = nka;
    }

    #pragma unroll
    for (int r = 0; r < QB; ++r) sm[r][kA] = acc[r];
    __syncthreads();

    {
        const int r   = w & 3;
        const int seg = w >> 2;
        float s[4];
        #pragma unroll
        for (int t = 0; t < 4; ++t) s[t] = sm[r][seg*256 + t*64 + lane];

        float m = fmaxf(fmaxf(s[0], s[1]), fmaxf(s[2], s[3]));
        #pragma unroll
        for (int off = 32; off >= 1; off >>= 1) m = fmaxf(m, __shfl_xor(m, off, 64));
        if (lane == 0) pmax[r][seg] = m;
        __syncthreads();

        float M = fmaxf(fmaxf(pmax[r][0], pmax[r][1]), fmaxf(pmax[r][2], pmax[r][3]));
        float sum = 0.f;
        #pragma unroll
        for (int t = 0; t < 4; ++t){ s[t] = __builtin_amdgcn_exp2f((s[t] - M) * LOG2E); sum += s[t]; }
        #pragma unroll
        for (int off = 32; off >= 1; off >>= 1) sum += __shfl_xor(sum, off, 64);
        if (lane == 0) psum[r][seg] = sum;
        __syncthreads();

        float S = (psum[r][0] + psum[r][1]) + (psum[r][2] + psum[r][3]);
        float inv = 1.0f / S;

        float* arow = attn + ((size_t)b * TQ + q0 + r) * TV + seg*256;
        #pragma unroll
        for (int t = 0; t < 4; ++t) arow[t*64 + lane] = s[t] * inv;
    }
}

// ---------------- context = attn @ value via bf16-split MFMA ----------------
// A converted in-kernel (coalesced fp32 rows); V from precomputed transposed planes.
// Tile 64x64, K-step 64, 4 waves (2x2), 24 MFMA/tile/wave.
__global__ __launch_bounds__(256)
void ctx_kernel(const float* __restrict__ attn,
                const unsigned short* __restrict__ vht, const unsigned short* __restrict__ vlt,
                float* __restrict__ ctx){
    __shared__ unsigned short Ah[64*64], Al[64*64], Vh[64*64], Vl[64*64];

    const int m0   = blockIdx.x * 64;
    const int n0   = blockIdx.y * 64;
    const int b    = m0 >> 10;
    const int tid  = threadIdx.x;
    const int lane = tid & 63;
    const int w    = tid >> 6;
    const int wm   = w >> 1, wn = w & 1;

    const int am = tid >> 2;            // A row / V col this thread stages
    const int kq = (tid & 3) * 16;      // k chunk

    const float*          arow  = attn + (size_t)(m0 + am) * TV;
    const unsigned short* vhrow = vht + ((size_t)b * DD + n0 + am) * TV;
    const unsigned short* vlrow = vlt + ((size_t)b * DD + n0 + am) * TV;

    float ra[16];
    int4 rvh0, rvh1, rvl0, rvl1;
    #pragma unroll
    for (int i = 0; i < 4; ++i)
        *reinterpret_cast<float4*>(&ra[i*4]) = *reinterpret_cast<const float4*>(arow + kq + i*4);
    rvh0 = *reinterpret_cast<const int4*>(vhrow + kq);
    rvh1 = *reinterpret_cast<const int4*>(vhrow + kq + 8);
    rvl0 = *reinterpret_cast<const int4*>(vlrow + kq);
    rvl1 = *reinterpret_cast<const int4*>(vlrow + kq + 8);

    f32x4 acc[2][2];
    #pragma unroll
    for (int i = 0; i < 2; ++i)
        #pragma unroll
        for (int j = 0; j < 2; ++j)
            acc[i][j] = (f32x4){0.f, 0.f, 0.f, 0.f};

    for (int kt = 0; kt < TV; kt += 64){
        // stage A (convert fp32 -> h/l) and V (direct)
        const int g0 = ((kq >> 3) + 0) ^ (am & 7);
        const int g1 = ((kq >> 3) + 1) ^ (am & 7);
        #pragma unroll
        for (int gg = 0; gg < 2; ++gg){
            unsigned short h8[8], l8[8];
            #pragma unroll
            for (int e = 0; e < 8; ++e){
                float a = ra[gg*8 + e];
                unsigned short h = f2bf(a);
                h8[e] = h; l8[e] = f2bf(a - bf2f(h));
            }
            int g = gg ? g1 : g0;
            *reinterpret_cast<int4*>(&Ah[am*64 + g*8]) = *reinterpret_cast<const int4*>(h8);
            *reinterpret_cast<int4*>(&Al[am*64 + g*8]) = *reinterpret_cast<const int4*>(l8);
        }
        *reinterpret_cast<int4*>(&Vh[am*64 + g0*8]) = rvh0;
        *reinterpret_cast<int4*>(&Vh[am*64 + g1*8]) = rvh1;
        *reinterpret_cast<int4*>(&Vl[am*64 + g0*8]) = rvl0;
        *reinterpret_cast<int4*>(&Vl[am*64 + g1*8]) = rvl1;

        // prefetch next k-tile
        const int ktn = (kt + 64 < TV) ? kt + 64 : 0;
        #pragma unroll
        for (int i = 0; i < 4; ++i)
            *reinterpret_cast<float4*>(&ra[i*4]) = *reinterpret_cast<const float4*>(arow + ktn + kq + i*4);
        rvh0 = *reinterpret_cast<const int4*>(vhrow + ktn + kq);
        rvh1 = *reinterpret_cast<const int4*>(vhrow + ktn + kq + 8);
        rvl0 = *reinterpret_cast<const int4*>(vlrow + ktn + kq);
        rvl1 = *reinterpret_cast<const int4*>(vlrow + ktn + kq + 8);

        __syncthreads();

        #pragma unroll
        for (int kk = 0; kk < 2; ++kk){
            const int kg = kk*4 + (lane >> 4);
            const int g  = (kg ^ (lane & 7)) * 8;
            const int r0 = (wm*32 + (lane & 15)) * 64;
            const int c0 = (wn*32 + (lane & 15)) * 64;

            short8 a0h = *reinterpret_cast<const short8*>(&Ah[r0 + g]);
            short8 a1h = *reinterpret_cast<const short8*>(&Ah[r0 + 16*64 + g]);
            short8 a0l = *reinterpret_cast<const short8*>(&Al[r0 + g]);
            short8 a1l = *reinterpret_cast<const short8*>(&Al[r0 + 16*64 + g]);
            short8 b0h = *reinterpret_cast<const short8*>(&Vh[c0 + g]);
            short8 b1h = *reinterpret_cast<const short8*>(&Vh[c0 + 16*64 + g]);
            short8 b0l = *reinterpret_cast<const short8*>(&Vl[c0 + g]);
            short8 b1l = *reinterpret_cast<const short8*>(&Vl[c0 + 16*64 + g]);

            acc[0][0] = __builtin_amdgcn_mfma_f32_16x16x32_bf16(a0h, b0h, acc[0][0], 0, 0, 0);
            acc[0][0] = __builtin_amdgcn_mfma_f32_16x16x32_bf16(a0l, b0h, acc[0][0], 0, 0, 0);
            acc[0][0] = __builtin_amdgcn_mfma_f32_16x16x32_bf16(a0h, b0l, acc[0][0], 0, 0, 0);

            acc[0][1] = __builtin_amdgcn_mfma_f32_16x16x32_bf16(a0h, b1h, acc[0][1], 0, 0, 0);
            acc[0][1] = __builtin_amdgcn_mfma_f32_16x16x32_bf16(a0l, b1h, acc[0][1], 0, 0, 0);
            acc[0][1] = __builtin_amdgcn_mfma_f32_16x16x32_bf16(a0h, b1l, acc[0][1], 0, 0, 0);

            acc[1][0] = __builtin_amdgcn_mfma_f32_16x16x32_bf16(a1h, b0h, acc[1][0], 0, 0, 0);
            acc[1][0] = __builtin_amdgcn_mfma_f32_16x16x32_bf16(a1l, b0h, acc[1][0], 0, 0, 0);
            acc[1][0] = __builtin_amdgcn_mfma_f32_16x16x32_bf16(a1h, b0l, acc[1][0], 0, 0, 0);

            acc[1][1] = __builtin_amdgcn_mfma_f32_16x16x32_bf16(a1h, b1h, acc[1][1], 0, 0, 0);
            acc[1][1] = __builtin_amdgcn_mfma_f32_16x16x32_bf16(a1l, b1h, acc[1][1], 0, 0, 0);
            acc[1][1] = __builtin_amdgcn_mfma_f32_16x16x32_bf16(a1h, b1l, acc[1][1], 0, 0, 0);
        }

        __syncthreads();
    }

    #pragma unroll
    for (int fm = 0; fm < 2; ++fm){
        #pragma unroll
        for (int fn = 0; fn < 2; ++fn){
            const int row = m0 + wm*32 + fm*16 + (lane >> 4) * 4;
            const int col = n0 + wn*32 + fn*16 + (lane & 15);
            #pragma unroll
            for (int r = 0; r < 4; ++r)
                ctx[(size_t)(row + r) * DD + col] = acc[fm][fn][r];
        }
    }
}

extern "C" void kernel_launch(void* const* d_in, const int* in_sizes, int n_in,
                              void* d_out, int out_size, void* d_ws, size_t ws_size,
                              hipStream_t stream){
    const float* query = (const float*)d_in[0];
    const float* value = (const float*)d_in[1];
    const float* W1    = (const float*)d_in[2];
    const float* W2    = (const float*)d_in[3];
    const float* scale = (const float*)d_in[4];

    float* eq = (float*)d_ws;                              // 1 MB
    float* ek = eq + (size_t)B_ * TQ * UU;                 // 1 MB
    unsigned short* vht = (unsigned short*)(ek + (size_t)B_ * TV * UU);   // 2 MB
    unsigned short* vlt = vht + (size_t)B_ * DD * TV;                     // 2 MB

    float* out  = (float*)d_out;
    float* ctx  = out;                                     // [B][TQ][DD]
    float* attn = out + (size_t)B_ * TQ * DD;              // [B][TQ][TV]

    proj_kernel<<<dim3(TQ/8, B_, 2), 256, 0, stream>>>(query, value, W1, W2, eq, ek);
    vsplit_kernel<<<dim3(TV/64, DD/64, B_), 256, 0, stream>>>(value, vht, vlt);
    fused_kernel<<<dim3(TQ/QB, B_), 1024, 0, stream>>>(eq, ek, scale, attn);
    ctx_kernel<<<dim3((B_*TQ)/64, DD/64), 256, 0, stream>>>(attn, vht, vlt, ctx);
}